// Round 14
// baseline (233.500 us; speedup 1.0000x reference)
//
#include <hip/hip_runtime.h>
#include <hip/hip_bf16.h>
#include <stdint.h>

typedef __bf16 bf16_t;
typedef bf16_t bf16x8 __attribute__((ext_vector_type(8)));
typedef bf16_t bf16x4 __attribute__((ext_vector_type(4)));
typedef float f32x4 __attribute__((ext_vector_type(4)));

// H=8 D=31 T=4 P=50 C=248 O=744 B=512, DT=124, SCALE=31^-0.5
constexpr float SCALE = 0.17960530202677491f;

__device__ __forceinline__ f32x4 mfma16(bf16x8 a, bf16x8 b, f32x4 c) {
    return __builtin_amdgcn_mfma_f32_16x16x32_bf16(a, b, c, 0, 0, 0);
}
__device__ __forceinline__ void fence() {
    asm volatile("s_waitcnt lgkmcnt(0)" ::: "memory");
}
__device__ __forceinline__ void gload_lds16(const void* g, void* l) {
    __builtin_amdgcn_global_load_lds((const __attribute__((address_space(1))) void*)g,
                                     (__attribute__((address_space(3))) void*)l, 16, 0, 0);
}

// ---------------------------------------------------------------------------
// prep: WT[768][256] bf16 (zero pad annihilates XT k-pad garbage),
// relf frag-packed (rt 0..6, rows 99..111 zero).
// ---------------------------------------------------------------------------
__global__ void prep_kernel(const float* __restrict__ w, const float* __restrict__ rel,
                            bf16_t* __restrict__ WT, bf16_t* __restrict__ relf)
{
    int i = blockIdx.x * 256 + threadIdx.x;
    if (i < 196608) {                    // WT: 768*256
        int o = i >> 8, c = i & 255;
        WT[i] = (o < 744 && c < 248) ? (bf16_t)w[(long)o * 248 + c] : (bf16_t)0.f;
        return;
    }
    i -= 196608;
    if (i < 14336) {                     // relf: rt 0..6 frag blocks
        int e = i & 7, lane = (i >> 3) & 63;
        int f = i >> 9;                  // rt*4+ks
        int ks = f & 3, rt = f >> 2;
        int r = rt * 16 + (lane & 15);
        int dt = ks * 32 + (lane >> 4) * 8 + e;
        float v = 0.f;
        if (r < 99 && dt < 124) v = rel[r * 124 + dt];
        relf[i] = (bf16_t)v;
    }
}

// ---------------------------------------------------------------------------
// xb: transpose+convert x[b][c][n] f32 -> XT[nflat][248] bf16 (rows 496 B).
// ---------------------------------------------------------------------------
__global__ void __launch_bounds__(512)
xb_kernel(const float* __restrict__ x, bf16_t* __restrict__ XT)
{
    __shared__ __align__(16) char XS[31744];       // [64 n][248 k] bf16
    const int tid = threadIdx.x;
    const int blk = blockIdx.x;                    // 0..1599
    const int cl = tid & 63;
    const int cg = tid >> 6;
    {
        int f = blk * 64 + cl;
        int b = f / 200;
        int nn = f - b * 200;
        const float* xp = x + (long)b * 49600 + nn;
#pragma unroll
        for (int ii = 0; ii < 4; ++ii) {
            int cb = cg + 8 * ii;                  // 16B chunk 0..31
            if (cb < 31) {
                bf16x8 pk;
#pragma unroll
                for (int e = 0; e < 8; ++e)
                    pk[e] = (bf16_t)xp[(long)(cb * 8 + e) * 200];
                *(bf16x8*)(XS + cl * 496 + cb * 16) = pk;
            }
        }
    }
    __syncthreads();
    if (tid < 496) {
        char* dst = (char*)XT + (long)blk * 31744 + tid * 64;
#pragma unroll
        for (int j = 0; j < 4; ++j)
            *(f32x4*)(dst + j * 16) = *(const f32x4*)(XS + tid * 64 + j * 16);
    }
}

// ---------------------------------------------------------------------------
// qkv GEMM, stage-once free-run: block = 64n x 256o (grid 1600 x 3).
// A-panel [64][256] bf16 staged ONCE to LDS (32 KB, source-XOR swizzle
// chunk^=(row&31) so frag reads are bank-spread), single barrier, then each
// wave owns o-slice wv*64: K-loop = ds_read A + rolling-prefetch B direct
// from L2-resident WT + 16 MFMA, NO further barriers (free-running waves).
// ---------------------------------------------------------------------------
__global__ void __launch_bounds__(256)
qkv_kernel(const bf16_t* __restrict__ XT, const bf16_t* __restrict__ WT,
           const float* __restrict__ bqkv, bf16_t* __restrict__ qk,
           bf16_t* __restrict__ vbuf)
{
    __shared__ __align__(16) char SM[32768];   // A: [64 rows][32 chunks of 16B]
    const int blk = blockIdx.x;                // 0..4799
    const int ntile = blk / 3, ot = blk - ntile * 3;
    const int n0 = ntile * 64, o0 = ot * 256;
    const int tid  = threadIdx.x;
    const int lane = tid & 63;
    const int wv   = tid >> 6;                 // 0..3: o-slice
    const int r15  = lane & 15, g4 = lane >> 4;

    const char* XTb = (const char*)XT;
    const char* WTb = (const char*)WT;

    // ---- stage A once: 8 sweeps x 4 KB ----
#pragma unroll
    for (int s = 0; s < 8; ++s) {
        int idx = s * 256 + tid;               // 0..2047
        int row = idx >> 5;                    // 0..63
        int cL  = idx & 31;                    // LDS chunk
        int cS  = cL ^ (row & 31);             // source chunk (involution)
        gload_lds16(XTb + (long)(n0 + row) * 496 + cS * 16,
                    SM + ((s * 256 + (tid & ~63)) << 4));
    }
    __syncthreads();

    // ---- free-run K-loop: wave-private ----
    f32x4 acc[4][4];
#pragma unroll
    for (int a = 0; a < 4; ++a)
#pragma unroll
        for (int b = 0; b < 4; ++b) acc[a][b] = f32x4{0.f, 0.f, 0.f, 0.f};

    const char* wB = WTb + (long)(o0 + wv * 64 + r15) * 512;
    bf16x8 Bc[4], Bn[4];
#pragma unroll
    for (int fo = 0; fo < 4; ++fo)
        Bc[fo] = *(const bf16x8*)(wB + fo * 16 * 512 + g4 * 16);

    for (int ks = 0; ks < 8; ++ks) {
        if (ks < 7) {
#pragma unroll
            for (int fo = 0; fo < 4; ++fo)
                Bn[fo] = *(const bf16x8*)(wB + fo * 16 * 512 + ((ks + 1) * 4 + g4) * 16);
        }
        bf16x8 Af[4];
#pragma unroll
        for (int fn = 0; fn < 4; ++fn) {
            int row = fn * 16 + r15;
            int cL = (ks * 4 + g4) ^ (row & 31);
            Af[fn] = *(const bf16x8*)(SM + row * 512 + cL * 16);
        }
#pragma unroll
        for (int fn = 0; fn < 4; ++fn)
#pragma unroll
            for (int fo = 0; fo < 4; ++fo)
                acc[fn][fo] = mfma16(Af[fn], Bc[fo], acc[fn][fo]);
#pragma unroll
        for (int fo = 0; fo < 4; ++fo) Bc[fo] = Bn[fo];
    }

    // ---- epilogue: all-packed bf16x4 stores ----
#pragma unroll
    for (int fo = 0; fo < 4; ++fo) {
        int o = o0 + wv * 64 + fo * 16 + r15;
        bool vo = (o < 744);
        int s = (o >= 496) ? 2 : ((o >= 248) ? 1 : 0);
        int rem = o - s * 248;
        int h = rem / 31;
        int d = rem - h * 31;
        float bias = vo ? bqkv[o] : 0.f;
        float sc = (s == 0) ? SCALE : 1.f;
#pragma unroll
        for (int fn = 0; fn < 4; ++fn) {
            int n = n0 + fn * 16 + g4 * 4;
            int b = n / 200;
            int p = (n - b * 200) >> 2;            // t = acc element j
            long bh = (long)(b * 8 + h);
            if (vo) {
                f32x4 a = acc[fn][fo];
                bf16x4 pk = {(bf16_t)((a[0] + bias) * sc), (bf16_t)((a[1] + bias) * sc),
                             (bf16_t)((a[2] + bias) * sc), (bf16_t)((a[3] + bias) * sc)};
                if (s < 2)
                    *(bf16x4*)(qk + (long)s * 26214400 + (bh * 50 + p) * 128 + d * 4) = pk;
                else
                    *(bf16x4*)(vbuf + bh * 8192 + p * 128 + d * 4) = pk;
            }
        }
    }
}

// ---------------------------------------------------------------------------
// Attention (R12-proven): 1 block per (b,h), 256 thr = 4 waves, ~35 KB LDS.
// In-LDS v transpose; wave-private dots + trimmed rel + softmax
// (unnormalized AS, RS scale in PV).
// ---------------------------------------------------------------------------
__global__ void __launch_bounds__(256)
attn_kernel(const bf16_t* __restrict__ qk, const bf16_t* __restrict__ vbuf,
            const bf16_t* __restrict__ relf, float* __restrict__ out)
{
    __shared__ float LS[50][52];
    __shared__ __align__(16) char AS[8192];    // exp[p][64] bf16, swz row&7
    __shared__ __align__(16) char VT[16384];   // vT[128 i][64 p] bf16, swz i&7
    __shared__ float RS[64];                   // 1/sum per row
    const int bid = blockIdx.x;
    const int bb = bid >> 3, hh = bid & 7;
    const int tid  = threadIdx.x;
    const int lane = tid & 63;
    const int w    = tid >> 6;                 // 0..3 = q-tile
    const int r15  = lane & 15, g4 = lane >> 4;

    const bf16_t* qB = qk + (long)bid * 6400;
    const bf16_t* kB = qk + 26214400L + (long)bid * 6400;
    const bf16_t* vB = vbuf + (long)bid * 8192;

    // ---- stage v[p][128] -> VT[i][p] (transposed, swizzled 16B chunks) ----
    {
        int p_ = tid >> 2, cc = tid & 3;
#pragma unroll
        for (int u = 0; u < 4; ++u) {
            int c = cc + u * 4;                // i-chunk 0..15
            bf16x8 vv = *(const bf16x8*)(vB + p_ * 128 + c * 8);
#pragma unroll
            for (int e = 0; e < 8; ++e) {
                int i = c * 8 + e;
                *(bf16_t*)(VT + i * 128 + (((p_ >> 3) ^ (i & 7)) << 4) + (p_ & 7) * 2) = vv[e];
            }
        }
    }

    // ---- q fragments (pre-scaled by SCALE) ----
    bf16x8 Afr[4];
#pragma unroll
    for (int ks = 0; ks < 4; ++ks)
        Afr[ks] = *(const bf16x8*)(qB + (w * 16 + r15) * 128 + ks * 32 + g4 * 8);

    // ---- dots ----
#pragma unroll
    for (int ct = 0; ct < 4; ++ct) {
        int c = ct * 16 + r15;
        f32x4 sA = f32x4{0.f, 0.f, 0.f, 0.f};
#pragma unroll
        for (int ks = 0; ks < 4; ++ks) {
            bf16x8 Bf = *(const bf16x8*)(kB + c * 128 + ks * 32 + g4 * 8);
            sA = mfma16(Afr[ks], Bf, sA);
        }
        if (c < 50) {
#pragma unroll
            for (int j = 0; j < 4; ++j) {
                int qrow = w * 16 + g4 * 4 + j;
                if (qrow < 50) LS[qrow][c] = sA[j];
            }
        }
    }
    fence();

    // ---- rel bias, trimmed to needed rt range; jj = r + qrow - 49 ----
    {
        const int rt0 = (w < 2) ? (2 - w) : 0;
        const int rt1 = 6 - w;
        const bf16_t* rf = relf + lane * 8;
        for (int rt = rt0; rt <= rt1; ++rt) {
            bf16x8 R[4];
#pragma unroll
            for (int ks = 0; ks < 4; ++ks)
                R[ks] = *(const bf16x8*)(rf + ((rt * 4 + ks) << 9));
            f32x4 sA = f32x4{0.f, 0.f, 0.f, 0.f};
#pragma unroll
            for (int ks = 0; ks < 4; ++ks) sA = mfma16(Afr[ks], R[ks], sA);
            int r = rt * 16 + r15;
#pragma unroll
            for (int j = 0; j < 4; ++j) {
                int qrow = w * 16 + g4 * 4 + j;
                int jj = r + qrow - 49;
                if (qrow < 50 && jj >= 0 && jj < 50) LS[qrow][jj] += sA[j];
            }
        }
    }
    fence();

    // ---- softmax: 4 lanes/row; AS = exp (unnormalized), RS = 1/sum ----
    {
        int row = w * 16 + (lane >> 2);
        int quad = lane & 3;
        int hrow = row & 7;
        if (row < 50) {
            float mx = -1e30f;
            for (int jj = quad; jj < 50; jj += 4) mx = fmaxf(mx, LS[row][jj]);
            mx = fmaxf(mx, __shfl_xor(mx, 1));
            mx = fmaxf(mx, __shfl_xor(mx, 2));
            float sum = 0.f;
            for (int jj = quad; jj < 50; jj += 4) {
                float e = __expf(LS[row][jj] - mx);
                sum += e;
                *(bf16_t*)(AS + row * 128 + (((jj >> 3) ^ hrow) << 4) + (jj & 7) * 2) = (bf16_t)e;
            }
            for (int jj = 50 + quad; jj < 64; jj += 4)
                *(bf16_t*)(AS + row * 128 + (((jj >> 3) ^ hrow) << 4) + (jj & 7) * 2) = (bf16_t)0.f;
            sum += __shfl_xor(sum, 1);
            sum += __shfl_xor(sum, 2);
            if (quad == 0) RS[row] = 1.f / sum;
        } else {
            for (int jj = quad; jj < 64; jj += 4)
                *(bf16_t*)(AS + row * 128 + (((jj >> 3) ^ hrow) << 4) + (jj & 7) * 2) = (bf16_t)0.f;
        }
    }
    __syncthreads();   // AS + VT ready

    // ---- PV: wave w owns i-tiles {2w, 2w+1}; all 4 p-tiles ----
#pragma unroll
    for (int ii = 0; ii < 2; ++ii) {
        int itile = w * 2 + ii;
        int irow = itile * 16 + r15;
        bf16x8 Av[2];
#pragma unroll
        for (int ks = 0; ks < 2; ++ks)
            Av[ks] = *(const bf16x8*)(VT + irow * 128 + ((((ks << 2) | g4) ^ (irow & 7)) << 4));
        int dd = itile * 4 + g4;
#pragma unroll
        for (int pt = 0; pt < 4; ++pt) {
            int prow = pt * 16 + r15;
            int hp2 = prow & 7;
            f32x4 po = f32x4{0.f, 0.f, 0.f, 0.f};
#pragma unroll
            for (int ks = 0; ks < 2; ++ks) {
                bf16x8 Bs = *(const bf16x8*)(AS + prow * 128 + ((((ks << 2) | g4) ^ hp2) << 4));
                po = mfma16(Av[ks], Bs, po);
            }
            if (dd < 31 && prow < 50) {
                float rsv = RS[prow];
                po[0] *= rsv; po[1] *= rsv; po[2] *= rsv; po[3] *= rsv;
                *(f32x4*)(out + ((long)bb * 248 + hh * 31 + dd) * 200 + prow * 4) = po;
            }
        }
    }
}

// ---------------------------------------------------------------------------
extern "C" void kernel_launch(void* const* d_in, const int* in_sizes, int n_in,
                              void* d_out, int out_size, void* d_ws, size_t ws_size,
                              hipStream_t stream)
{
    const float* x   = (const float*)d_in[0];
    const float* wq  = (const float*)d_in[1];
    const float* bq  = (const float*)d_in[2];
    const float* rel = (const float*)d_in[3];
    float* out = (float*)d_out;

    char* ws = (char*)d_ws;
    bf16_t* WT   = (bf16_t*)ws;                    // 393,216 B
    bf16_t* relf = (bf16_t*)(ws + 393216);         // 28,672 B
    bf16_t* qk   = (bf16_t*)(ws + 421888);         // q+k: 104,857,600 B
    bf16_t* vbuf = qk + 52428800L;                 // v slots: 67,108,864 B
    // ws used: 172,388,352 B (proven)

    bf16_t* XT = (bf16_t*)d_out;                   // 50.79 MB; dead before attn

    const int B = in_sizes[0] / 49600;             // 512

    prep_kernel<<<dim3(824), dim3(256), 0, stream>>>(wq, rel, WT, relf);
    xb_kernel<<<dim3(B * 200 / 64), dim3(512), 0, stream>>>(x, XT);
    qkv_kernel<<<dim3(4800), dim3(256), 0, stream>>>(XT, WT, bq, qk, vbuf);
    attn_kernel<<<dim3(B * 8), dim3(256), 0, stream>>>(qk, vbuf, relf, out);
}

// Round 15
// 198.233 us; speedup vs baseline: 1.1779x; 1.1779x over previous
//
#include <hip/hip_runtime.h>
#include <hip/hip_bf16.h>
#include <stdint.h>

typedef __bf16 bf16_t;
typedef bf16_t bf16x8 __attribute__((ext_vector_type(8)));
typedef bf16_t bf16x4 __attribute__((ext_vector_type(4)));
typedef float f32x4 __attribute__((ext_vector_type(4)));

// H=8 D=31 T=4 P=50 C=248 O=744 B=512, DT=124, SCALE=31^-0.5
constexpr float SCALE = 0.17960530202677491f;

__device__ __forceinline__ f32x4 mfma16(bf16x8 a, bf16x8 b, f32x4 c) {
    return __builtin_amdgcn_mfma_f32_16x16x32_bf16(a, b, c, 0, 0, 0);
}
__device__ __forceinline__ void fence() {
    asm volatile("s_waitcnt lgkmcnt(0)" ::: "memory");
}
__device__ __forceinline__ void gload_lds16(const void* g, void* l) {
    __builtin_amdgcn_global_load_lds((const __attribute__((address_space(1))) void*)g,
                                     (__attribute__((address_space(3))) void*)l, 16, 0, 0);
}

// ---------------------------------------------------------------------------
// prep: WT[768][256] bf16 (zero pad annihilates XT k-pad garbage),
// relf frag-packed (rt 0..6, rows 99..111 zero).
// ---------------------------------------------------------------------------
__global__ void prep_kernel(const float* __restrict__ w, const float* __restrict__ rel,
                            bf16_t* __restrict__ WT, bf16_t* __restrict__ relf)
{
    int i = blockIdx.x * 256 + threadIdx.x;
    if (i < 196608) {                    // WT: 768*256
        int o = i >> 8, c = i & 255;
        WT[i] = (o < 744 && c < 248) ? (bf16_t)w[(long)o * 248 + c] : (bf16_t)0.f;
        return;
    }
    i -= 196608;
    if (i < 14336) {                     // relf: rt 0..6 frag blocks
        int e = i & 7, lane = (i >> 3) & 63;
        int f = i >> 9;                  // rt*4+ks
        int ks = f & 3, rt = f >> 2;
        int r = rt * 16 + (lane & 15);
        int dt = ks * 32 + (lane >> 4) * 8 + e;
        float v = 0.f;
        if (r < 99 && dt < 124) v = rel[r * 124 + dt];
        relf[i] = (bf16_t)v;
    }
}

// ---------------------------------------------------------------------------
// xb: transpose+convert x[b][c][n] f32 -> XT[nflat][248] bf16 (rows 496 B).
// ---------------------------------------------------------------------------
__global__ void __launch_bounds__(512)
xb_kernel(const float* __restrict__ x, bf16_t* __restrict__ XT)
{
    __shared__ __align__(16) char XS[31744];       // [64 n][248 k] bf16
    const int tid = threadIdx.x;
    const int blk = blockIdx.x;                    // 0..1599
    const int cl = tid & 63;
    const int cg = tid >> 6;
    {
        int f = blk * 64 + cl;
        int b = f / 200;
        int nn = f - b * 200;
        const float* xp = x + (long)b * 49600 + nn;
#pragma unroll
        for (int ii = 0; ii < 4; ++ii) {
            int cb = cg + 8 * ii;                  // 16B chunk 0..31
            if (cb < 31) {
                bf16x8 pk;
#pragma unroll
                for (int e = 0; e < 8; ++e)
                    pk[e] = (bf16_t)xp[(long)(cb * 8 + e) * 200];
                *(bf16x8*)(XS + cl * 496 + cb * 16) = pk;
            }
        }
    }
    __syncthreads();
    if (tid < 496) {
        char* dst = (char*)XT + (long)blk * 31744 + tid * 64;
#pragma unroll
        for (int j = 0; j < 4; ++j)
            *(f32x4*)(dst + j * 16) = *(const f32x4*)(XS + tid * 64 + j * 16);
    }
}

// ---------------------------------------------------------------------------
// qkv GEMM: C[n][o] = XT[n][k] * WT[o][k], tile 256n x 128o, BK=32, 8 K-steps,
// 512 thr = 8 waves (4x2), per-wave 64x64 (acc[4][4], ~110 VGPR). A+B both
// dbuf-staged via global_load_lds w16 (48 KB LDS). 2400 blocks, XCD-swizzled.
// Epilogue: q/k -> qk[s][bh][50][128] (q pre-scaled); v -> vbuf[bh][p][128].
// ---------------------------------------------------------------------------
__global__ void __launch_bounds__(512)
qkv_kernel(const bf16_t* __restrict__ XT, const bf16_t* __restrict__ WT,
           const float* __restrict__ bqkv, bf16_t* __restrict__ qk,
           bf16_t* __restrict__ vbuf)
{
    __shared__ __align__(16) char SM[49152];   // A: buf*16384; B: 32768+buf*8192
    const int raw = blockIdx.x;                // 2400 = 8*300
    const int swz = (raw & 7) * 300 + (raw >> 3);
    const int mt = swz % 6, nt = swz / 6;      // nt 0..399
    const int n0 = nt * 256, o0 = mt * 128;
    const int tid  = threadIdx.x;
    const int lane = tid & 63;
    const int wv   = tid >> 6;                 // 0..7
    const int r15  = lane & 15, g4 = lane >> 4;
    const int kc   = lane & 3, rsub = lane >> 2;
    const int wr = wv >> 1, wc = wv & 1;       // wave grid 4x2

    f32x4 acc[4][4];
#pragma unroll
    for (int a = 0; a < 4; ++a)
#pragma unroll
        for (int b = 0; b < 4; ++b) acc[a][b] = f32x4{0.f, 0.f, 0.f, 0.f};

    const char* XTb = (const char*)XT;
    const char* WTb = (const char*)WT;

#define STAGE(BUF, KS)                                                          \
    {                                                                           \
        _Pragma("unroll")                                                       \
        for (int i_ = 0; i_ < 2; ++i_) {                                        \
            int r0 = (wv * 2 + i_) * 16;                                        \
            int row = r0 + rsub;                                                \
            gload_lds16(XTb + (long)(n0 + row) * 496 + ((KS) * 4 + kc) * 16,    \
                        SM + (BUF) * 16384 + r0 * 64);                          \
        }                                                                       \
        {                                                                       \
            int r0 = wv * 16;                                                   \
            int row = r0 + rsub;                                                \
            gload_lds16(WTb + (long)(o0 + row) * 512 + ((KS) * 4 + kc) * 16,    \
                        SM + 32768 + (BUF) * 8192 + r0 * 64);                   \
        }                                                                       \
    }

    STAGE(0, 0);
    __syncthreads();

    int buf = 0;
    for (int ks = 0; ks < 8; ++ks) {
        if (ks < 7) STAGE(buf ^ 1, ks + 1);
        bf16x8 Af[4], Bf[4];
#pragma unroll
        for (int fn = 0; fn < 4; ++fn) {
            int row = wr * 64 + fn * 16 + r15;
            Af[fn] = *(const bf16x8*)(SM + buf * 16384 + row * 64 + g4 * 16);
        }
#pragma unroll
        for (int fo = 0; fo < 4; ++fo) {
            int row = wc * 64 + fo * 16 + r15;
            Bf[fo] = *(const bf16x8*)(SM + 32768 + buf * 8192 + row * 64 + g4 * 16);
        }
#pragma unroll
        for (int fn = 0; fn < 4; ++fn)
#pragma unroll
            for (int fo = 0; fo < 4; ++fo)
                acc[fn][fo] = mfma16(Af[fn], Bf[fo], acc[fn][fo]);
        __syncthreads();
        buf ^= 1;
    }
#undef STAGE

    // ---- epilogue: all-packed bf16x4 stores ----
#pragma unroll
    for (int fo = 0; fo < 4; ++fo) {
        int o = o0 + wc * 64 + fo * 16 + r15;
        bool vo = (o < 744);
        int s = (o >= 496) ? 2 : ((o >= 248) ? 1 : 0);
        int rem = o - s * 248;
        int h = rem / 31;
        int d = rem - h * 31;
        float bias = vo ? bqkv[o] : 0.f;
        float sc = (s == 0) ? SCALE : 1.f;
#pragma unroll
        for (int fn = 0; fn < 4; ++fn) {
            int n = n0 + wr * 64 + fn * 16 + g4 * 4;
            int b = n / 200;
            int p = (n - b * 200) >> 2;            // t = acc element j
            long bh = (long)(b * 8 + h);
            if (vo) {
                f32x4 a = acc[fn][fo];
                bf16x4 pk = {(bf16_t)((a[0] + bias) * sc), (bf16_t)((a[1] + bias) * sc),
                             (bf16_t)((a[2] + bias) * sc), (bf16_t)((a[3] + bias) * sc)};
                if (s < 2)
                    *(bf16x4*)(qk + (long)s * 26214400 + (bh * 50 + p) * 128 + d * 4) = pk;
                else
                    *(bf16x4*)(vbuf + bh * 8192 + p * 128 + d * 4) = pk;
            }
        }
    }
}

// ---------------------------------------------------------------------------
// Attention (R12-proven): 1 block per (b,h), 256 thr = 4 waves, ~35 KB LDS.
// In-LDS v transpose; wave-private dots + trimmed rel + softmax
// (unnormalized AS, RS scale in PV).
// ---------------------------------------------------------------------------
__global__ void __launch_bounds__(256)
attn_kernel(const bf16_t* __restrict__ qk, const bf16_t* __restrict__ vbuf,
            const bf16_t* __restrict__ relf, float* __restrict__ out)
{
    __shared__ float LS[50][52];
    __shared__ __align__(16) char AS[8192];    // exp[p][64] bf16, swz row&7
    __shared__ __align__(16) char VT[16384];   // vT[128 i][64 p] bf16, swz i&7
    __shared__ float RS[64];                   // 1/sum per row
    const int bid = blockIdx.x;
    const int bb = bid >> 3, hh = bid & 7;
    const int tid  = threadIdx.x;
    const int lane = tid & 63;
    const int w    = tid >> 6;                 // 0..3 = q-tile
    const int r15  = lane & 15, g4 = lane >> 4;

    const bf16_t* qB = qk + (long)bid * 6400;
    const bf16_t* kB = qk + 26214400L + (long)bid * 6400;
    const bf16_t* vB = vbuf + (long)bid * 8192;

    // ---- stage v[p][128] -> VT[i][p] (transposed, swizzled 16B chunks) ----
    {
        int p_ = tid >> 2, cc = tid & 3;
#pragma unroll
        for (int u = 0; u < 4; ++u) {
            int c = cc + u * 4;                // i-chunk 0..15
            bf16x8 vv = *(const bf16x8*)(vB + p_ * 128 + c * 8);
#pragma unroll
            for (int e = 0; e < 8; ++e) {
                int i = c * 8 + e;
                *(bf16_t*)(VT + i * 128 + (((p_ >> 3) ^ (i & 7)) << 4) + (p_ & 7) * 2) = vv[e];
            }
        }
    }

    // ---- q fragments (pre-scaled by SCALE) ----
    bf16x8 Afr[4];
#pragma unroll
    for (int ks = 0; ks < 4; ++ks)
        Afr[ks] = *(const bf16x8*)(qB + (w * 16 + r15) * 128 + ks * 32 + g4 * 8);

    // ---- dots ----
#pragma unroll
    for (int ct = 0; ct < 4; ++ct) {
        int c = ct * 16 + r15;
        f32x4 sA = f32x4{0.f, 0.f, 0.f, 0.f};
#pragma unroll
        for (int ks = 0; ks < 4; ++ks) {
            bf16x8 Bf = *(const bf16x8*)(kB + c * 128 + ks * 32 + g4 * 8);
            sA = mfma16(Afr[ks], Bf, sA);
        }
        if (c < 50) {
#pragma unroll
            for (int j = 0; j < 4; ++j) {
                int qrow = w * 16 + g4 * 4 + j;
                if (qrow < 50) LS[qrow][c] = sA[j];
            }
        }
    }
    fence();

    // ---- rel bias, trimmed to needed rt range; jj = r + qrow - 49 ----
    {
        const int rt0 = (w < 2) ? (2 - w) : 0;
        const int rt1 = 6 - w;
        const bf16_t* rf = relf + lane * 8;
        for (int rt = rt0; rt <= rt1; ++rt) {
            bf16x8 R[4];
#pragma unroll
            for (int ks = 0; ks < 4; ++ks)
                R[ks] = *(const bf16x8*)(rf + ((rt * 4 + ks) << 9));
            f32x4 sA = f32x4{0.f, 0.f, 0.f, 0.f};
#pragma unroll
            for (int ks = 0; ks < 4; ++ks) sA = mfma16(Afr[ks], R[ks], sA);
            int r = rt * 16 + r15;
#pragma unroll
            for (int j = 0; j < 4; ++j) {
                int qrow = w * 16 + g4 * 4 + j;
                int jj = r + qrow - 49;
                if (qrow < 50 && jj >= 0 && jj < 50) LS[qrow][jj] += sA[j];
            }
        }
    }
    fence();

    // ---- softmax: 4 lanes/row; AS = exp (unnormalized), RS = 1/sum ----
    {
        int row = w * 16 + (lane >> 2);
        int quad = lane & 3;
        int hrow = row & 7;
        if (row < 50) {
            float mx = -1e30f;
            for (int jj = quad; jj < 50; jj += 4) mx = fmaxf(mx, LS[row][jj]);
            mx = fmaxf(mx, __shfl_xor(mx, 1));
            mx = fmaxf(mx, __shfl_xor(mx, 2));
            float sum = 0.f;
            for (int jj = quad; jj < 50; jj += 4) {
                float e = __expf(LS[row][jj] - mx);
                sum += e;
                *(bf16_t*)(AS + row * 128 + (((jj >> 3) ^ hrow) << 4) + (jj & 7) * 2) = (bf16_t)e;
            }
            for (int jj = 50 + quad; jj < 64; jj += 4)
                *(bf16_t*)(AS + row * 128 + (((jj >> 3) ^ hrow) << 4) + (jj & 7) * 2) = (bf16_t)0.f;
            sum += __shfl_xor(sum, 1);
            sum += __shfl_xor(sum, 2);
            if (quad == 0) RS[row] = 1.f / sum;
        } else {
            for (int jj = quad; jj < 64; jj += 4)
                *(bf16_t*)(AS + row * 128 + (((jj >> 3) ^ hrow) << 4) + (jj & 7) * 2) = (bf16_t)0.f;
        }
    }
    __syncthreads();   // AS + VT ready

    // ---- PV: wave w owns i-tiles {2w, 2w+1}; all 4 p-tiles ----
#pragma unroll
    for (int ii = 0; ii < 2; ++ii) {
        int itile = w * 2 + ii;
        int irow = itile * 16 + r15;
        bf16x8 Av[2];
#pragma unroll
        for (int ks = 0; ks < 2; ++ks)
            Av[ks] = *(const bf16x8*)(VT + irow * 128 + ((((ks << 2) | g4) ^ (irow & 7)) << 4));
        int dd = itile * 4 + g4;
#pragma unroll
        for (int pt = 0; pt < 4; ++pt) {
            int prow = pt * 16 + r15;
            int hp2 = prow & 7;
            f32x4 po = f32x4{0.f, 0.f, 0.f, 0.f};
#pragma unroll
            for (int ks = 0; ks < 2; ++ks) {
                bf16x8 Bs = *(const bf16x8*)(AS + prow * 128 + ((((ks << 2) | g4) ^ hp2) << 4));
                po = mfma16(Av[ks], Bs, po);
            }
            if (dd < 31 && prow < 50) {
                float rsv = RS[prow];
                po[0] *= rsv; po[1] *= rsv; po[2] *= rsv; po[3] *= rsv;
                *(f32x4*)(out + ((long)bb * 248 + hh * 31 + dd) * 200 + prow * 4) = po;
            }
        }
    }
}

// ---------------------------------------------------------------------------
extern "C" void kernel_launch(void* const* d_in, const int* in_sizes, int n_in,
                              void* d_out, int out_size, void* d_ws, size_t ws_size,
                              hipStream_t stream)
{
    const float* x   = (const float*)d_in[0];
    const float* wq  = (const float*)d_in[1];
    const float* bq  = (const float*)d_in[2];
    const float* rel = (const float*)d_in[3];
    float* out = (float*)d_out;

    char* ws = (char*)d_ws;
    bf16_t* WT   = (bf16_t*)ws;                    // 393,216 B
    bf16_t* relf = (bf16_t*)(ws + 393216);         // 28,672 B
    bf16_t* qk   = (bf16_t*)(ws + 421888);         // q+k: 104,857,600 B
    bf16_t* vbuf = qk + 52428800L;                 // v slots: 67,108,864 B
    // ws used: 172,388,352 B (proven)

    bf16_t* XT = (bf16_t*)d_out;                   // 50.79 MB; dead before attn

    const int B = in_sizes[0] / 49600;             // 512

    prep_kernel<<<dim3(824), dim3(256), 0, stream>>>(wq, rel, WT, relf);
    xb_kernel<<<dim3(B * 200 / 64), dim3(512), 0, stream>>>(x, XT);
    qkv_kernel<<<dim3(2400), dim3(512), 0, stream>>>(XT, WT, bq, qk, vbuf);
    attn_kernel<<<dim3(B * 8), dim3(256), 0, stream>>>(qk, vbuf, relf, out);
}

// Round 16
// 197.510 us; speedup vs baseline: 1.1822x; 1.0037x over previous
//
#include <hip/hip_runtime.h>
#include <hip/hip_bf16.h>
#include <stdint.h>

typedef __bf16 bf16_t;
typedef bf16_t bf16x8 __attribute__((ext_vector_type(8)));
typedef bf16_t bf16x4 __attribute__((ext_vector_type(4)));
typedef float f32x4 __attribute__((ext_vector_type(4)));

// H=8 D=31 T=4 P=50 C=248 O=744 B=512, DT=124, SCALE=31^-0.5
constexpr float SCALE = 0.17960530202677491f;

__device__ __forceinline__ f32x4 mfma16(bf16x8 a, bf16x8 b, f32x4 c) {
    return __builtin_amdgcn_mfma_f32_16x16x32_bf16(a, b, c, 0, 0, 0);
}
__device__ __forceinline__ void fence() {
    asm volatile("s_waitcnt lgkmcnt(0)" ::: "memory");
}
__device__ __forceinline__ void gload_lds16(const void* g, void* l) {
    __builtin_amdgcn_global_load_lds((const __attribute__((address_space(1))) void*)g,
                                     (__attribute__((address_space(3))) void*)l, 16, 0, 0);
}

// ---------------------------------------------------------------------------
// prep: WT[768][256] bf16 (zero pad annihilates XT k-pad garbage),
// relf frag-packed (rt 0..6, rows 99..111 zero).
// ---------------------------------------------------------------------------
__global__ void prep_kernel(const float* __restrict__ w, const float* __restrict__ rel,
                            bf16_t* __restrict__ WT, bf16_t* __restrict__ relf)
{
    int i = blockIdx.x * 256 + threadIdx.x;
    if (i < 196608) {                    // WT: 768*256
        int o = i >> 8, c = i & 255;
        WT[i] = (o < 744 && c < 248) ? (bf16_t)w[(long)o * 248 + c] : (bf16_t)0.f;
        return;
    }
    i -= 196608;
    if (i < 14336) {                     // relf: rt 0..6 frag blocks
        int e = i & 7, lane = (i >> 3) & 63;
        int f = i >> 9;                  // rt*4+ks
        int ks = f & 3, rt = f >> 2;
        int r = rt * 16 + (lane & 15);
        int dt = ks * 32 + (lane >> 4) * 8 + e;
        float v = 0.f;
        if (r < 99 && dt < 124) v = rel[r * 124 + dt];
        relf[i] = (bf16_t)v;
    }
}

// ---------------------------------------------------------------------------
// xb: transpose+convert x[b][c][n] f32 -> XT[nflat][248] bf16 (rows 496 B).
// ---------------------------------------------------------------------------
__global__ void __launch_bounds__(512)
xb_kernel(const float* __restrict__ x, bf16_t* __restrict__ XT)
{
    __shared__ __align__(16) char XS[31744];       // [64 n][248 k] bf16
    const int tid = threadIdx.x;
    const int blk = blockIdx.x;                    // 0..1599
    const int cl = tid & 63;
    const int cg = tid >> 6;
    {
        int f = blk * 64 + cl;
        int b = f / 200;
        int nn = f - b * 200;
        const float* xp = x + (long)b * 49600 + nn;
#pragma unroll
        for (int ii = 0; ii < 4; ++ii) {
            int cb = cg + 8 * ii;                  // 16B chunk 0..31
            if (cb < 31) {
                bf16x8 pk;
#pragma unroll
                for (int e = 0; e < 8; ++e)
                    pk[e] = (bf16_t)xp[(long)(cb * 8 + e) * 200];
                *(bf16x8*)(XS + cl * 496 + cb * 16) = pk;
            }
        }
    }
    __syncthreads();
    if (tid < 496) {
        char* dst = (char*)XT + (long)blk * 31744 + tid * 64;
#pragma unroll
        for (int j = 0; j < 4; ++j)
            *(f32x4*)(dst + j * 16) = *(const f32x4*)(XS + tid * 64 + j * 16);
    }
}

// ---------------------------------------------------------------------------
// qkv GEMM: C[n][o] = XT[n][k] * WT[o][k], tile 256n x 128o, BK=32, 8 K-steps,
// 512 thr = 8 waves (4x2). A+B dbuf via global_load_lds w16 (48 KB LDS).
// LDS bank-conflict fix (rule #21): data(row,chunk) stored at slot chunk
// chunk^((row>>1)&3) -- linear dest, inverse-swizzled SOURCE, swizzled READ.
// Turns the 8-way ds_read_b128 conflict (row stride 64B) into 2-way (free).
// ---------------------------------------------------------------------------
__global__ void __launch_bounds__(512)
qkv_kernel(const bf16_t* __restrict__ XT, const bf16_t* __restrict__ WT,
           const float* __restrict__ bqkv, bf16_t* __restrict__ qk,
           bf16_t* __restrict__ vbuf)
{
    __shared__ __align__(16) char SM[49152];   // A: buf*16384; B: 32768+buf*8192
    const int raw = blockIdx.x;                // 2400 = 8*300
    const int swz = (raw & 7) * 300 + (raw >> 3);
    const int mt = swz % 6, nt = swz / 6;      // nt 0..399
    const int n0 = nt * 256, o0 = mt * 128;
    const int tid  = threadIdx.x;
    const int lane = tid & 63;
    const int wv   = tid >> 6;                 // 0..7
    const int r15  = lane & 15, g4 = lane >> 4;
    const int kc   = lane & 3, rsub = lane >> 2;
    const int wr = wv >> 1, wc = wv & 1;       // wave grid 4x2

    f32x4 acc[4][4];
#pragma unroll
    for (int a = 0; a < 4; ++a)
#pragma unroll
        for (int b = 0; b < 4; ++b) acc[a][b] = f32x4{0.f, 0.f, 0.f, 0.f};

    const char* XTb = (const char*)XT;
    const char* WTb = (const char*)WT;

    // Per-lane inverse-swizzled source chunk: kc ^ ((row>>1)&3).
#define STAGE(BUF, KS)                                                            \
    {                                                                             \
        _Pragma("unroll")                                                         \
        for (int i_ = 0; i_ < 2; ++i_) {                                          \
            int r0 = (wv * 2 + i_) * 16;                                          \
            int row = r0 + rsub;                                                  \
            int cs = kc ^ ((row >> 1) & 3);                                       \
            gload_lds16(XTb + (long)(n0 + row) * 496 + ((KS) * 4 + cs) * 16,      \
                        SM + (BUF) * 16384 + r0 * 64);                            \
        }                                                                         \
        {                                                                         \
            int r0 = wv * 16;                                                     \
            int row = r0 + rsub;                                                  \
            int cs = kc ^ ((row >> 1) & 3);                                       \
            gload_lds16(WTb + (long)(o0 + row) * 512 + ((KS) * 4 + cs) * 16,      \
                        SM + 32768 + (BUF) * 8192 + r0 * 64);                     \
        }                                                                         \
    }

    STAGE(0, 0);
    __syncthreads();

    int buf = 0;
    for (int ks = 0; ks < 8; ++ks) {
        if (ks < 7) STAGE(buf ^ 1, ks + 1);
        bf16x8 Af[4], Bf[4];
#pragma unroll
        for (int fn = 0; fn < 4; ++fn) {
            int row = wr * 64 + fn * 16 + r15;
            int cr = g4 ^ ((row >> 1) & 3);
            Af[fn] = *(const bf16x8*)(SM + buf * 16384 + row * 64 + cr * 16);
        }
#pragma unroll
        for (int fo = 0; fo < 4; ++fo) {
            int row = wc * 64 + fo * 16 + r15;
            int cr = g4 ^ ((row >> 1) & 3);
            Bf[fo] = *(const bf16x8*)(SM + 32768 + buf * 8192 + row * 64 + cr * 16);
        }
#pragma unroll
        for (int fn = 0; fn < 4; ++fn)
#pragma unroll
            for (int fo = 0; fo < 4; ++fo)
                acc[fn][fo] = mfma16(Af[fn], Bf[fo], acc[fn][fo]);
        __syncthreads();
        buf ^= 1;
    }
#undef STAGE

    // ---- epilogue: all-packed bf16x4 stores ----
#pragma unroll
    for (int fo = 0; fo < 4; ++fo) {
        int o = o0 + wc * 64 + fo * 16 + r15;
        bool vo = (o < 744);
        int s = (o >= 496) ? 2 : ((o >= 248) ? 1 : 0);
        int rem = o - s * 248;
        int h = rem / 31;
        int d = rem - h * 31;
        float bias = vo ? bqkv[o] : 0.f;
        float sc = (s == 0) ? SCALE : 1.f;
#pragma unroll
        for (int fn = 0; fn < 4; ++fn) {
            int n = n0 + wr * 64 + fn * 16 + g4 * 4;
            int b = n / 200;
            int p = (n - b * 200) >> 2;            // t = acc element j
            long bh = (long)(b * 8 + h);
            if (vo) {
                f32x4 a = acc[fn][fo];
                bf16x4 pk = {(bf16_t)((a[0] + bias) * sc), (bf16_t)((a[1] + bias) * sc),
                             (bf16_t)((a[2] + bias) * sc), (bf16_t)((a[3] + bias) * sc)};
                if (s < 2)
                    *(bf16x4*)(qk + (long)s * 26214400 + (bh * 50 + p) * 128 + d * 4) = pk;
                else
                    *(bf16x4*)(vbuf + bh * 8192 + p * 128 + d * 4) = pk;
            }
        }
    }
}

// ---------------------------------------------------------------------------
// Attention (R12-proven): 1 block per (b,h), 256 thr = 4 waves, ~35 KB LDS.
// In-LDS v transpose; wave-private dots + trimmed rel + softmax
// (unnormalized AS, RS scale in PV).
// ---------------------------------------------------------------------------
__global__ void __launch_bounds__(256)
attn_kernel(const bf16_t* __restrict__ qk, const bf16_t* __restrict__ vbuf,
            const bf16_t* __restrict__ relf, float* __restrict__ out)
{
    __shared__ float LS[50][52];
    __shared__ __align__(16) char AS[8192];    // exp[p][64] bf16, swz row&7
    __shared__ __align__(16) char VT[16384];   // vT[128 i][64 p] bf16, swz i&7
    __shared__ float RS[64];                   // 1/sum per row
    const int bid = blockIdx.x;
    const int bb = bid >> 3, hh = bid & 7;
    const int tid  = threadIdx.x;
    const int lane = tid & 63;
    const int w    = tid >> 6;                 // 0..3 = q-tile
    const int r15  = lane & 15, g4 = lane >> 4;

    const bf16_t* qB = qk + (long)bid * 6400;
    const bf16_t* kB = qk + 26214400L + (long)bid * 6400;
    const bf16_t* vB = vbuf + (long)bid * 8192;

    // ---- stage v[p][128] -> VT[i][p] (transposed, swizzled 16B chunks) ----
    {
        int p_ = tid >> 2, cc = tid & 3;
#pragma unroll
        for (int u = 0; u < 4; ++u) {
            int c = cc + u * 4;                // i-chunk 0..15
            bf16x8 vv = *(const bf16x8*)(vB + p_ * 128 + c * 8);
#pragma unroll
            for (int e = 0; e < 8; ++e) {
                int i = c * 8 + e;
                *(bf16_t*)(VT + i * 128 + (((p_ >> 3) ^ (i & 7)) << 4) + (p_ & 7) * 2) = vv[e];
            }
        }
    }

    // ---- q fragments (pre-scaled by SCALE) ----
    bf16x8 Afr[4];
#pragma unroll
    for (int ks = 0; ks < 4; ++ks)
        Afr[ks] = *(const bf16x8*)(qB + (w * 16 + r15) * 128 + ks * 32 + g4 * 8);

    // ---- dots ----
#pragma unroll
    for (int ct = 0; ct < 4; ++ct) {
        int c = ct * 16 + r15;
        f32x4 sA = f32x4{0.f, 0.f, 0.f, 0.f};
#pragma unroll
        for (int ks = 0; ks < 4; ++ks) {
            bf16x8 Bf = *(const bf16x8*)(kB + c * 128 + ks * 32 + g4 * 8);
            sA = mfma16(Afr[ks], Bf, sA);
        }
        if (c < 50) {
#pragma unroll
            for (int j = 0; j < 4; ++j) {
                int qrow = w * 16 + g4 * 4 + j;
                if (qrow < 50) LS[qrow][c] = sA[j];
            }
        }
    }
    fence();

    // ---- rel bias, trimmed to needed rt range; jj = r + qrow - 49 ----
    {
        const int rt0 = (w < 2) ? (2 - w) : 0;
        const int rt1 = 6 - w;
        const bf16_t* rf = relf + lane * 8;
        for (int rt = rt0; rt <= rt1; ++rt) {
            bf16x8 R[4];
#pragma unroll
            for (int ks = 0; ks < 4; ++ks)
                R[ks] = *(const bf16x8*)(rf + ((rt * 4 + ks) << 9));
            f32x4 sA = f32x4{0.f, 0.f, 0.f, 0.f};
#pragma unroll
            for (int ks = 0; ks < 4; ++ks) sA = mfma16(Afr[ks], R[ks], sA);
            int r = rt * 16 + r15;
#pragma unroll
            for (int j = 0; j < 4; ++j) {
                int qrow = w * 16 + g4 * 4 + j;
                int jj = r + qrow - 49;
                if (qrow < 50 && jj >= 0 && jj < 50) LS[qrow][jj] += sA[j];
            }
        }
    }
    fence();

    // ---- softmax: 4 lanes/row; AS = exp (unnormalized), RS = 1/sum ----
    {
        int row = w * 16 + (lane >> 2);
        int quad = lane & 3;
        int hrow = row & 7;
        if (row < 50) {
            float mx = -1e30f;
            for (int jj = quad; jj < 50; jj += 4) mx = fmaxf(mx, LS[row][jj]);
            mx = fmaxf(mx, __shfl_xor(mx, 1));
            mx = fmaxf(mx, __shfl_xor(mx, 2));
            float sum = 0.f;
            for (int jj = quad; jj < 50; jj += 4) {
                float e = __expf(LS[row][jj] - mx);
                sum += e;
                *(bf16_t*)(AS + row * 128 + (((jj >> 3) ^ hrow) << 4) + (jj & 7) * 2) = (bf16_t)e;
            }
            for (int jj = 50 + quad; jj < 64; jj += 4)
                *(bf16_t*)(AS + row * 128 + (((jj >> 3) ^ hrow) << 4) + (jj & 7) * 2) = (bf16_t)0.f;
            sum += __shfl_xor(sum, 1);
            sum += __shfl_xor(sum, 2);
            if (quad == 0) RS[row] = 1.f / sum;
        } else {
            for (int jj = quad; jj < 64; jj += 4)
                *(bf16_t*)(AS + row * 128 + (((jj >> 3) ^ hrow) << 4) + (jj & 7) * 2) = (bf16_t)0.f;
        }
    }
    __syncthreads();   // AS + VT ready

    // ---- PV: wave w owns i-tiles {2w, 2w+1}; all 4 p-tiles ----
#pragma unroll
    for (int ii = 0; ii < 2; ++ii) {
        int itile = w * 2 + ii;
        int irow = itile * 16 + r15;
        bf16x8 Av[2];
#pragma unroll
        for (int ks = 0; ks < 2; ++ks)
            Av[ks] = *(const bf16x8*)(VT + irow * 128 + ((((ks << 2) | g4) ^ (irow & 7)) << 4));
        int dd = itile * 4 + g4;
#pragma unroll
        for (int pt = 0; pt < 4; ++pt) {
            int prow = pt * 16 + r15;
            int hp2 = prow & 7;
            f32x4 po = f32x4{0.f, 0.f, 0.f, 0.f};
#pragma unroll
            for (int ks = 0; ks < 2; ++ks) {
                bf16x8 Bs = *(const bf16x8*)(AS + prow * 128 + ((((ks << 2) | g4) ^ hp2) << 4));
                po = mfma16(Av[ks], Bs, po);
            }
            if (dd < 31 && prow < 50) {
                float rsv = RS[prow];
                po[0] *= rsv; po[1] *= rsv; po[2] *= rsv; po[3] *= rsv;
                *(f32x4*)(out + ((long)bb * 248 + hh * 31 + dd) * 200 + prow * 4) = po;
            }
        }
    }
}

// ---------------------------------------------------------------------------
extern "C" void kernel_launch(void* const* d_in, const int* in_sizes, int n_in,
                              void* d_out, int out_size, void* d_ws, size_t ws_size,
                              hipStream_t stream)
{
    const float* x   = (const float*)d_in[0];
    const float* wq  = (const float*)d_in[1];
    const float* bq  = (const float*)d_in[2];
    const float* rel = (const float*)d_in[3];
    float* out = (float*)d_out;

    char* ws = (char*)d_ws;
    bf16_t* WT   = (bf16_t*)ws;                    // 393,216 B
    bf16_t* relf = (bf16_t*)(ws + 393216);         // 28,672 B
    bf16_t* qk   = (bf16_t*)(ws + 421888);         // q+k: 104,857,600 B
    bf16_t* vbuf = qk + 52428800L;                 // v slots: 67,108,864 B
    // ws used: 172,388,352 B (proven)

    bf16_t* XT = (bf16_t*)d_out;                   // 50.79 MB; dead before attn

    const int B = in_sizes[0] / 49600;             // 512

    prep_kernel<<<dim3(824), dim3(256), 0, stream>>>(wq, rel, WT, relf);
    xb_kernel<<<dim3(B * 200 / 64), dim3(512), 0, stream>>>(x, XT);
    qkv_kernel<<<dim3(2400), dim3(512), 0, stream>>>(XT, WT, bq, qk, vbuf);
    attn_kernel<<<dim3(B * 8), dim3(256), 0, stream>>>(qk, vbuf, relf, out);
}